// Round 15
// baseline (161.152 us; speedup 1.0000x reference)
//
#include <hip/hip_runtime.h>
#include <hip/hip_bf16.h>
#include <hip/hip_fp16.h>
#include <cstddef>
#include <cstdint>

typedef __attribute__((ext_vector_type(8))) short bf16x8;
typedef __attribute__((ext_vector_type(4))) float f32x4;

#define MFMA16(a, b, c) __builtin_amdgcn_mfma_f32_16x16x32_bf16((a), (b), (c), 0, 0, 0)

static constexpr int B = 4, S = 512, HID = 768, NH = 12, HD = 64;
static constexpr int QKV_N = B * NH * S * HD;              // 1,572,864
static constexpr size_t SCORES_N = (size_t)B * NH * S * S; // 12,582,912
static constexpr int WT_N  = 768 * 768;

__device__ __forceinline__ short f2bf(float f) {
  unsigned u = __builtin_bit_cast(unsigned, f);
  u += 0x7FFFu + ((u >> 16) & 1u);
  return (short)(u >> 16);
}
__device__ __forceinline__ short f2bf_c(float f) {
  __hip_bfloat16 h = __float2bfloat16(f);
  return *reinterpret_cast<short*>(&h);
}
__device__ __forceinline__ float h2f(short s) {
  __half h = __builtin_bit_cast(__half, (unsigned short)s);
  return __half2float(h);
}
__device__ __forceinline__ bf16x8 ld_cvt8(const float* __restrict__ p) {
  float4 a = *reinterpret_cast<const float4*>(p);
  float4 b = *reinterpret_cast<const float4*>(p + 4);
  bf16x8 r;
  r[0] = f2bf(a.x); r[1] = f2bf(a.y); r[2] = f2bf(a.z); r[3] = f2bf(a.w);
  r[4] = f2bf(b.x); r[5] = f2bf(b.y); r[6] = f2bf(b.z); r[7] = f2bf(b.w);
  return r;
}
__device__ __forceinline__ f32x4 ld4nt(const float* p) {
  return __builtin_nontemporal_load(reinterpret_cast<const f32x4*>(p));
}
__device__ __forceinline__ bf16x8 cvt8(f32x4 a, f32x4 b) {
  bf16x8 r;
  r[0] = f2bf_c(a[0]); r[1] = f2bf_c(a[1]); r[2] = f2bf_c(a[2]); r[3] = f2bf_c(a[3]);
  r[4] = f2bf_c(b[0]); r[5] = f2bf_c(b[1]); r[6] = f2bf_c(b[2]); r[7] = f2bf_c(b[3]);
  return r;
}

// ---------------------------------------------------------------------------
// K0 (prep, role A removed): blk [0,432): Wq/Wk/Wv -> WbT[mat][n][k] bf16
//   (transposed); blk [432,444): WqrT = 0.125*(Wq_h @ Wr^T)^T, bqr.
// ---------------------------------------------------------------------------
__global__ __launch_bounds__(256) void k_prep(
    const float* __restrict__ Wq, const float* __restrict__ Wk,
    const float* __restrict__ Wv, const float* __restrict__ Wr,
    const float* __restrict__ bq,
    short* __restrict__ WbT, short* __restrict__ WqrT,
    float* __restrict__ bqr) {
  __shared__ short tile[64 * 72];
  const int blk = blockIdx.x;
  const int t = threadIdx.x;
  if (blk < 432) {
    int mat = blk / 144, rest = blk % 144;
    int kt = (rest / 12) * 64, nt = (rest % 12) * 64;
    const float* __restrict__ W = (mat == 0) ? Wq : (mat == 1) ? Wk : Wv;
    int r0 = t >> 2, c0 = (t & 3) * 16;
#pragma unroll
    for (int u = 0; u < 16; u += 4) {
      float4 v = *reinterpret_cast<const float4*>(W + (size_t)(kt + r0) * 768 + nt + c0 + u);
      tile[(c0 + u + 0) * 72 + r0] = f2bf(v.x);
      tile[(c0 + u + 1) * 72 + r0] = f2bf(v.y);
      tile[(c0 + u + 2) * 72 + r0] = f2bf(v.z);
      tile[(c0 + u + 3) * 72 + r0] = f2bf(v.w);
    }
    __syncthreads();
    short* dst = WbT + (size_t)mat * WT_N + (size_t)(nt + r0) * 768 + kt + c0;
    *reinterpret_cast<bf16x8*>(dst)     = *reinterpret_cast<const bf16x8*>(&tile[r0 * 72 + c0]);
    *reinterpret_cast<bf16x8*>(dst + 8) = *reinterpret_cast<const bf16x8*>(&tile[r0 * 72 + c0 + 8]);
    return;
  }
  const int h = blk - 432;
  if (t < 64) {
    float s = 0.f;
#pragma unroll
    for (int d = 0; d < 64; ++d) s += bq[h * 64 + d] * Wr[t * 64 + d];
    bqr[h * 64 + t] = 0.125f * s;
  }
  const int w = t >> 6, lane = t & 63;
  const int wm = (w >> 1) * 32, wn = (w & 1) * 32;
  const int lr = lane & 15, lk = lane >> 4;
  for (int kt = 0; kt < 768; kt += 64) {
    f32x4 acc[2][2] = {};
#pragma unroll
    for (int ks = 0; ks < 2; ++ks) {
      int d0 = ks * 32 + lk * 8;
      bf16x8 a0 = ld_cvt8(Wr + (size_t)(wm + lr) * 64 + d0);
      bf16x8 a1 = ld_cvt8(Wr + (size_t)(wm + 16 + lr) * 64 + d0);
      bf16x8 b0 = ld_cvt8(Wq + (size_t)(kt + wn + lr) * 768 + h * 64 + d0);
      bf16x8 b1 = ld_cvt8(Wq + (size_t)(kt + wn + 16 + lr) * 768 + h * 64 + d0);
      acc[0][0] = MFMA16(a0, b0, acc[0][0]);
      acc[0][1] = MFMA16(a0, b1, acc[0][1]);
      acc[1][0] = MFMA16(a1, b0, acc[1][0]);
      acc[1][1] = MFMA16(a1, b1, acc[1][1]);
    }
#pragma unroll
    for (int mf = 0; mf < 2; ++mf)
#pragma unroll
      for (int nf = 0; nf < 2; ++nf) {
        int kcol = kt + wn + nf * 16 + lr;
#pragma unroll
        for (int reg = 0; reg < 4; ++reg) {
          int r = wm + mf * 16 + lk * 4 + reg;
          WqrT[(size_t)(h * 64 + r) * 768 + kcol] = f2bf(0.125f * acc[mf][nf][reg]);
        }
      }
  }
}

// ---------------------------------------------------------------------------
// K1: projection GEMM, 128x128 tile, BK=32. A staged DIRECTLY from x (f32,
// converted in staging -- same f2bf bits as the old prep pass). B from
// pre-transposed bf16 weights. N = 4 mats x 768 (24 n-blocks).
// ---------------------------------------------------------------------------
__global__ __launch_bounds__(256) void k_qkv4(
    const float* __restrict__ x, const short* __restrict__ WbT,
    const short* __restrict__ WqrT,
    const float* __restrict__ bq, const float* __restrict__ bk,
    const float* __restrict__ bv, const float* __restrict__ bqr,
    short* __restrict__ qkv, short* __restrict__ qrb, short* __restrict__ vT) {
  __shared__ short As[128 * 40];
  __shared__ short Bs[128 * 40];
  const int m0 = blockIdx.x * 128;
  const int nb = blockIdx.y;              // 0..23
  const int mat = nb / 6;
  const int n0 = (nb % 6) * 128;
  const short* __restrict__ Bp =
      (mat < 3) ? WbT + (size_t)mat * WT_N + (size_t)n0 * 768
                : WqrT + (size_t)n0 * 768;
  const float* __restrict__ bias =
      (mat == 0) ? bq : (mat == 1) ? bk : (mat == 2) ? bv : bqr;
  const int t = threadIdx.x;
  const int w = t >> 6, lane = t & 63;
  const int wm = (w >> 1) * 64, wn = (w & 1) * 64;
  const int lr = lane & 15, lk = lane >> 4;
  const int srow = t >> 1, shalf = (t & 1) * 16;
  const float* ga = x + (size_t)(m0 + srow) * 768 + shalf;
  const short* gb = Bp + (size_t)srow * 768 + shalf;
  f32x4 acc[4][4] = {};
  for (int kk = 0; kk < 768; kk += 32) {
    {
      const float* sa = ga + kk;
      *reinterpret_cast<bf16x8*>(&As[srow * 40 + shalf]) = ld_cvt8(sa);
      *reinterpret_cast<bf16x8*>(&As[srow * 40 + shalf + 8]) = ld_cvt8(sa + 8);
      const short* sb = gb + kk;
      *reinterpret_cast<bf16x8*>(&Bs[srow * 40 + shalf])     = *reinterpret_cast<const bf16x8*>(sb);
      *reinterpret_cast<bf16x8*>(&Bs[srow * 40 + shalf + 8]) = *reinterpret_cast<const bf16x8*>(sb + 8);
    }
    __syncthreads();
    bf16x8 af[4], bf[4];
#pragma unroll
    for (int mf = 0; mf < 4; ++mf)
      af[mf] = *reinterpret_cast<const bf16x8*>(&As[(wm + mf * 16 + lr) * 40 + lk * 8]);
#pragma unroll
    for (int nf = 0; nf < 4; ++nf)
      bf[nf] = *reinterpret_cast<const bf16x8*>(&Bs[(wn + nf * 16 + lr) * 40 + lk * 8]);
#pragma unroll
    for (int mf = 0; mf < 4; ++mf)
#pragma unroll
      for (int nf = 0; nf < 4; ++nf)
        acc[mf][nf] = MFMA16(af[mf], bf[nf], acc[mf][nf]);
    __syncthreads();
  }
  const int b_ = m0 >> 9;
#pragma unroll
  for (int mf = 0; mf < 4; ++mf)
#pragma unroll
    for (int nf = 0; nf < 4; ++nf) {
      int col = n0 + wn + nf * 16 + lr;
      float bv_ = bias[col];
      int h0 = col >> 6, d = col & 63;
#pragma unroll
      for (int reg = 0; reg < 4; ++reg) {
        int i = (m0 + wm + mf * 16 + lk * 4 + reg) & 511;
        float val = acc[mf][nf][reg] + bv_;
        if (mat == 2) {
          vT[((size_t)(b_ * NH + h0) * HD + d) * S + i] = f2bf(val);
        } else if (mat == 3) {
          qrb[((size_t)(b_ * NH + h0) * S + i) * 64 + d] = f2bf(val);
        } else {
          qkv[(size_t)mat * QKV_N + (size_t)((b_ * NH + h0) * S + i) * HD + d] = f2bf(val);
        }
      }
    }
}

// ---------------------------------------------------------------------------
// K3: PURE qk scores -> f16 [b][i][h][j], no mask (mask applied in relsm).
// ---------------------------------------------------------------------------
__global__ __launch_bounds__(256) void k_qk(const short* __restrict__ q,
                                            const short* __restrict__ kmat,
                                            __half* __restrict__ sc) {
  const int j0 = blockIdx.x * 64, i0 = blockIdx.y * 64;
  const int bh = blockIdx.z;
  const int b = bh / NH, hh = bh % NH;
  const short* __restrict__ qp = q + (size_t)(bh * S) * HD;
  const short* __restrict__ kp = kmat + (size_t)(bh * S) * HD;
  const int t = threadIdx.x;
  const int w = t >> 6, lane = t & 63;
  const int wm = (w >> 1) * 32, wn = (w & 1) * 32;
  const int lr = lane & 15, lk = lane >> 4;
  f32x4 acc[2][2] = {};
#pragma unroll
  for (int ks = 0; ks < 2; ++ks) {
    int k0 = ks * 32 + lk * 8;
    bf16x8 a0 = *reinterpret_cast<const bf16x8*>(qp + (size_t)(i0 + wm + lr) * 64 + k0);
    bf16x8 a1 = *reinterpret_cast<const bf16x8*>(qp + (size_t)(i0 + wm + 16 + lr) * 64 + k0);
    bf16x8 b0 = *reinterpret_cast<const bf16x8*>(kp + (size_t)(j0 + wn + lr) * 64 + k0);
    bf16x8 b1 = *reinterpret_cast<const bf16x8*>(kp + (size_t)(j0 + wn + 16 + lr) * 64 + k0);
    acc[0][0] = MFMA16(a0, b0, acc[0][0]);
    acc[0][1] = MFMA16(a0, b1, acc[0][1]);
    acc[1][0] = MFMA16(a1, b0, acc[1][0]);
    acc[1][1] = MFMA16(a1, b1, acc[1][1]);
  }
#pragma unroll
  for (int mf = 0; mf < 2; ++mf)
#pragma unroll
    for (int nf = 0; nf < 2; ++nf) {
      int j = j0 + wn + nf * 16 + lr;
#pragma unroll
      for (int reg = 0; reg < 4; ++reg) {
        int i = i0 + wm + mf * 16 + lk * 4 + reg;
        sc[(((size_t)b * S + i) * NH + hh) * S + j] = __float2half(acc[mf][nf][reg] * 0.125f);
      }
    }
}

// ---------------------------------------------------------------------------
// K4: per (b,i): s = sc[h,j] + mask[j] + qr.rel^T; p = exp(min(s,80));
// den-reduce; probs bf16 via LDS repack. 2-DEEP rel prefetch: per-tt compute
// (~100cy) + TLP doesn't cover ~900cy HBM latency at 1-deep.
// ---------------------------------------------------------------------------
__global__ __launch_bounds__(256) void k_relsm(const short* __restrict__ qrb,
                                               const float* __restrict__ rel,
                                               const __half* __restrict__ sc,
                                               const float* __restrict__ graph,
                                               const float* __restrict__ endm,
                                               short* __restrict__ probs) {
  __shared__ short sq[16 * 520];
  __shared__ float mask_lds[512];
  __shared__ float den_lds[64];
  const int i = blockIdx.x, b = blockIdx.y;
  const int t = threadIdx.x;
  const int w = t >> 6, lane = t & 63;
  const int lr = lane & 15, fq = lane >> 4;
  {
    const short* src = reinterpret_cast<const short*>(sc + ((size_t)(b * S) + i) * NH * S);
    int hh = t >> 4, js = (t & 15) * 32;
    const short* sp = src + (size_t)hh * S + js;
    short* dp = &sq[hh * 520 + js];
#pragma unroll
    for (int c = 0; c < 4; ++c)
      *reinterpret_cast<bf16x8*>(dp + c * 8) = *reinterpret_cast<const bf16x8*>(sp + c * 8);
  }
  {
    int j = t * 2;
    float2 g = *reinterpret_cast<const float2*>(graph + ((size_t)b * S + i) * S + j);
    float2 e = *reinterpret_cast<const float2*>(endm + (size_t)b * S + j);
    mask_lds[j]     = (1.0f - g.x - e.x) * (-30000.0f);
    mask_lds[j + 1] = (1.0f - g.y - e.y) * (-30000.0f);
  }
  const int hA = (lr < NH) ? lr : 0;
  const short* qrow = qrb + ((size_t)(b * NH + hA) * S + i) * 64;
  bf16x8 a0 = *reinterpret_cast<const bf16x8*>(qrow + fq * 8);
  bf16x8 a1 = *reinterpret_cast<const bf16x8*>(qrow + 32 + fq * 8);
  const float* rp = rel + (((size_t)(b * S) + i) * S + (size_t)(w * 128 + lr)) * 64 + fq * 8;
  float p[8][4];
  float den[4] = {0.f, 0.f, 0.f, 0.f};
  // 2-deep software pipeline on the rel stream
  f32x4 c0 = ld4nt(rp), c1 = ld4nt(rp + 4), c2 = ld4nt(rp + 32), c3 = ld4nt(rp + 36);
  f32x4 d0 = ld4nt(rp + 1024), d1 = ld4nt(rp + 1028),
        d2 = ld4nt(rp + 1056), d3 = ld4nt(rp + 1060);
  __syncthreads();
#pragma unroll
  for (int tt = 0; tt < 8; ++tt) {
    f32x4 e0, e1, e2, e3;
    if (tt < 6) {
      const float* rn = rp + (size_t)(tt + 2) * 1024;
      e0 = ld4nt(rn); e1 = ld4nt(rn + 4); e2 = ld4nt(rn + 32); e3 = ld4nt(rn + 36);
    }
    bf16x8 b0 = cvt8(c0, c1), b1 = cvt8(c2, c3);
    f32x4 acc = {};
    acc = MFMA16(a0, b0, acc);
    acc = MFMA16(a1, b1, acc);
    const int j0 = w * 128 + tt * 16;
    const float mval = mask_lds[j0 + lr];
#pragma unroll
    for (int r = 0; r < 4; ++r) {
      int h = fq * 4 + r;
      float s = acc[r] + h2f(sq[h * 520 + j0 + lr]) + mval;
      float pe = __expf(fminf(s, 80.0f));
      den[r] += pe;
      p[tt][r] = pe;
    }
    c0 = d0; c1 = d1; c2 = d2; c3 = d3;
    if (tt < 6) { d0 = e0; d1 = e1; d2 = e2; d3 = e3; }
  }
#pragma unroll
  for (int r = 0; r < 4; ++r) {
    float d = den[r];
    d += __shfl_xor(d, 1); d += __shfl_xor(d, 2);
    d += __shfl_xor(d, 4); d += __shfl_xor(d, 8);
    den[r] = d;
  }
  if (lr == 0) {
#pragma unroll
    for (int r = 0; r < 4; ++r) den_lds[w * 16 + fq * 4 + r] = den[r];
  }
  __syncthreads();
  float invd[4];
#pragma unroll
  for (int r = 0; r < 4; ++r) {
    int h = fq * 4 + r;
    invd[r] = 1.0f / (den_lds[h] + den_lds[16 + h] + den_lds[32 + h] + den_lds[48 + h]);
  }
#pragma unroll
  for (int tt = 0; tt < 8; ++tt) {
    int j0 = w * 128 + tt * 16;
#pragma unroll
    for (int r = 0; r < 4; ++r) {
      int h = fq * 4 + r;
      sq[h * 520 + j0 + lr] = f2bf(p[tt][r] * invd[r]);
    }
  }
  __syncthreads();
  {
    const int h = t >> 4, jseg = t & 15;
    if (h < NH) {
      short* op = probs + ((size_t)(b * NH + h) * S + i) * S + jseg * 32;
      const short* lp = &sq[h * 520 + jseg * 32];
#pragma unroll
      for (int c = 0; c < 4; ++c)
        *reinterpret_cast<bf16x8*>(op + c * 8) = *reinterpret_cast<const bf16x8*>(lp + c * 8);
    }
  }
}

// ---------------------------------------------------------------------------
// K5: ctx = probs @ v via MFMA, LDS-free (vT[b,h,d,j]).
// ---------------------------------------------------------------------------
__global__ __launch_bounds__(256) void k_pv2(const short* __restrict__ probs,
                                             const short* __restrict__ vT,
                                             float* __restrict__ out) {
  const int i0 = blockIdx.x * 32;
  const int h = blockIdx.y, b = blockIdx.z;
  const short* __restrict__ pp  = probs + (size_t)((b * NH + h) * S) * S;
  const short* __restrict__ vtp = vT + (size_t)((b * NH + h) * HD) * S;
  const int t = threadIdx.x;
  const int w = t >> 6, lane = t & 63;
  const int wm = (w >> 1) * 16, wn = (w & 1) * 32;
  const int lr = lane & 15, lk = lane >> 4;
  f32x4 acc[2] = {};
#pragma unroll
  for (int j0 = 0; j0 < S; j0 += 64) {
#pragma unroll
    for (int ks = 0; ks < 2; ++ks) {
      int k0 = j0 + ks * 32 + lk * 8;
      bf16x8 a0 = *reinterpret_cast<const bf16x8*>(pp + (size_t)(i0 + wm + lr) * S + k0);
      bf16x8 b0 = *reinterpret_cast<const bf16x8*>(vtp + (size_t)(wn + lr) * S + k0);
      bf16x8 b1 = *reinterpret_cast<const bf16x8*>(vtp + (size_t)(wn + 16 + lr) * S + k0);
      acc[0] = MFMA16(a0, b0, acc[0]);
      acc[1] = MFMA16(a0, b1, acc[1]);
    }
  }
#pragma unroll
  for (int nf = 0; nf < 2; ++nf) {
    int d = wn + nf * 16 + lr;
#pragma unroll
    for (int reg = 0; reg < 4; ++reg) {
      int i = i0 + wm + lk * 4 + reg;
      out[((size_t)(b * S) + i) * HID + h * 64 + d] = acc[nf][reg];
    }
  }
}

// ---------------------------------------------------------------------------
extern "C" void kernel_launch(void* const* d_in, const int* in_sizes, int n_in,
                              void* d_out, int out_size, void* d_ws, size_t ws_size,
                              hipStream_t stream) {
  const float* x     = (const float*)d_in[0];
  const float* graph = (const float*)d_in[1];
  const float* endm  = (const float*)d_in[2];
  const float* rel   = (const float*)d_in[3];
  const float* Wq = (const float*)d_in[4];  const float* bq = (const float*)d_in[5];
  const float* Wk = (const float*)d_in[6];  const float* bk = (const float*)d_in[7];
  const float* Wv = (const float*)d_in[8];  const float* bv = (const float*)d_in[9];
  const float* Wr = (const float*)d_in[10]; // br dropped: softmax-invariant

  short* WbT  = (short*)d_ws;                    // bf16 W^T x3
  short* WqrT = WbT + 3 * WT_N;                  // bf16 combined qr weight
  float* bqr  = (float*)(WqrT + WT_N);
  short* qb   = (short*)(bqr + 768);
  short* kb   = qb + QKV_N;
  short* vTb  = kb + QKV_N;                      // v transposed [b][h][d][j]
  short* qrb  = vTb + QKV_N;
  __half* scores = (__half*)(qrb + QKV_N);       // f16, [b][i][h][j] (unmasked)
  short* probs   = (short*)(scores + SCORES_N);  // bf16, [b][h][i][j]
  const size_t need = (size_t)(4 * WT_N) * 2 + 768 * 4 +
                      (size_t)4 * QKV_N * 2 + SCORES_N * 2 + SCORES_N * 2;
  if (ws_size < need) return;

  k_prep<<<dim3(444), 256, 0, stream>>>(Wq, Wk, Wv, Wr, bq, WbT, WqrT, bqr);
  k_qkv4<<<dim3(16, 24), 256, 0, stream>>>(x, WbT, WqrT, bq, bk, bv, bqr, qb, qrb, vTb);
  k_qk<<<dim3(8, 8, B * NH), 256, 0, stream>>>(qb, kb, scores);
  k_relsm<<<dim3(S, B), 256, 0, stream>>>(qrb, rel, scores, graph, endm, probs);
  k_pv2<<<dim3(16, NH, B), 256, 0, stream>>>(probs, vTb, (float*)d_out);
}

// Round 16
// 153.201 us; speedup vs baseline: 1.0519x; 1.0519x over previous
//
#include <hip/hip_runtime.h>
#include <hip/hip_bf16.h>
#include <hip/hip_fp16.h>
#include <cstddef>
#include <cstdint>

typedef __attribute__((ext_vector_type(8))) short bf16x8;
typedef __attribute__((ext_vector_type(4))) float f32x4;

#define MFMA16(a, b, c) __builtin_amdgcn_mfma_f32_16x16x32_bf16((a), (b), (c), 0, 0, 0)

static constexpr int B = 4, S = 512, HID = 768, NH = 12, HD = 64;
static constexpr int QKV_N = B * NH * S * HD;              // 1,572,864
static constexpr size_t SCORES_N = (size_t)B * NH * S * S; // 12,582,912
static constexpr int XB_N  = 2048 * 768;
static constexpr int WT_N  = 768 * 768;

__device__ __forceinline__ short f2bf(float f) {
  unsigned u = __builtin_bit_cast(unsigned, f);
  u += 0x7FFFu + ((u >> 16) & 1u);
  return (short)(u >> 16);
}
__device__ __forceinline__ float h2f(short s) {
  __half h = __builtin_bit_cast(__half, (unsigned short)s);
  return __half2float(h);
}
__device__ __forceinline__ bf16x8 ld_cvt8(const float* __restrict__ p) {
  float4 a = *reinterpret_cast<const float4*>(p);
  float4 b = *reinterpret_cast<const float4*>(p + 4);
  bf16x8 r;
  r[0] = f2bf(a.x); r[1] = f2bf(a.y); r[2] = f2bf(a.z); r[3] = f2bf(a.w);
  r[4] = f2bf(b.x); r[5] = f2bf(b.y); r[6] = f2bf(b.z); r[7] = f2bf(b.w);
  return r;
}
__device__ __forceinline__ f32x4 ld4nt(const float* p) {
  return __builtin_nontemporal_load(reinterpret_cast<const f32x4*>(p));
}
__device__ __forceinline__ bf16x8 cvt8(f32x4 a, f32x4 b) {
  bf16x8 r;
  r[0] = f2bf(a[0]); r[1] = f2bf(a[1]); r[2] = f2bf(a[2]); r[3] = f2bf(a[3]);
  r[4] = f2bf(b[0]); r[5] = f2bf(b[1]); r[6] = f2bf(b[2]); r[7] = f2bf(b[3]);
  return r;
}

// ---------------------------------------------------------------------------
// K0 (prep): role A blk [0,768): x -> xb bf16
//   role B blk [768,1200): Wq/Wk/Wv -> WbT[mat][n][k] bf16 (transposed)
//   role C blk [1200,1212): WqrT[h*64+r][k] = 0.125*(Wq_h @ Wr^T)^T, bqr
// ---------------------------------------------------------------------------
__global__ __launch_bounds__(256) void k_prep(
    const float* __restrict__ x,
    const float* __restrict__ Wq, const float* __restrict__ Wk,
    const float* __restrict__ Wv, const float* __restrict__ Wr,
    const float* __restrict__ bq,
    short* __restrict__ xb, short* __restrict__ WbT,
    short* __restrict__ WqrT, float* __restrict__ bqr) {
  __shared__ short tile[64 * 72];
  const int blk = blockIdx.x;
  const int t = threadIdx.x;
  if (blk < 768) {
    size_t base = (size_t)blk * 2048 + t * 8;
    *reinterpret_cast<bf16x8*>(xb + base) = ld_cvt8(x + base);
    return;
  }
  if (blk < 1200) {
    int q = blk - 768;
    int mat = q / 144, rest = q % 144;
    int kt = (rest / 12) * 64, nt = (rest % 12) * 64;
    const float* __restrict__ W = (mat == 0) ? Wq : (mat == 1) ? Wk : Wv;
    int r0 = t >> 2, c0 = (t & 3) * 16;
#pragma unroll
    for (int u = 0; u < 16; u += 4) {
      float4 v = *reinterpret_cast<const float4*>(W + (size_t)(kt + r0) * 768 + nt + c0 + u);
      tile[(c0 + u + 0) * 72 + r0] = f2bf(v.x);
      tile[(c0 + u + 1) * 72 + r0] = f2bf(v.y);
      tile[(c0 + u + 2) * 72 + r0] = f2bf(v.z);
      tile[(c0 + u + 3) * 72 + r0] = f2bf(v.w);
    }
    __syncthreads();
    short* dst = WbT + (size_t)mat * WT_N + (size_t)(nt + r0) * 768 + kt + c0;
    *reinterpret_cast<bf16x8*>(dst)     = *reinterpret_cast<const bf16x8*>(&tile[r0 * 72 + c0]);
    *reinterpret_cast<bf16x8*>(dst + 8) = *reinterpret_cast<const bf16x8*>(&tile[r0 * 72 + c0 + 8]);
    return;
  }
  const int h = blk - 1200;
  if (t < 64) {
    float s = 0.f;
#pragma unroll
    for (int d = 0; d < 64; ++d) s += bq[h * 64 + d] * Wr[t * 64 + d];
    bqr[h * 64 + t] = 0.125f * s;
  }
  const int w = t >> 6, lane = t & 63;
  const int wm = (w >> 1) * 32, wn = (w & 1) * 32;
  const int lr = lane & 15, lk = lane >> 4;
  for (int kt = 0; kt < 768; kt += 64) {
    f32x4 acc[2][2] = {};
#pragma unroll
    for (int ks = 0; ks < 2; ++ks) {
      int d0 = ks * 32 + lk * 8;
      bf16x8 a0 = ld_cvt8(Wr + (size_t)(wm + lr) * 64 + d0);
      bf16x8 a1 = ld_cvt8(Wr + (size_t)(wm + 16 + lr) * 64 + d0);
      bf16x8 b0 = ld_cvt8(Wq + (size_t)(kt + wn + lr) * 768 + h * 64 + d0);
      bf16x8 b1 = ld_cvt8(Wq + (size_t)(kt + wn + 16 + lr) * 768 + h * 64 + d0);
      acc[0][0] = MFMA16(a0, b0, acc[0][0]);
      acc[0][1] = MFMA16(a0, b1, acc[0][1]);
      acc[1][0] = MFMA16(a1, b0, acc[1][0]);
      acc[1][1] = MFMA16(a1, b1, acc[1][1]);
    }
#pragma unroll
    for (int mf = 0; mf < 2; ++mf)
#pragma unroll
      for (int nf = 0; nf < 2; ++nf) {
        int kcol = kt + wn + nf * 16 + lr;
#pragma unroll
        for (int reg = 0; reg < 4; ++reg) {
          int r = wm + mf * 16 + lk * 4 + reg;
          WqrT[(size_t)(h * 64 + r) * 768 + kcol] = f2bf(0.125f * acc[mf][nf][reg]);
        }
      }
  }
}

// ---------------------------------------------------------------------------
// K1: uniform projection GEMM, LDS-tiled bf16. M=2048, K=768 (BK=64),
// N = 48 blocks of 64 (q,k,v,qr).
// ---------------------------------------------------------------------------
__global__ __launch_bounds__(256) void k_qkv3(
    const short* __restrict__ xb, const short* __restrict__ WbT,
    const short* __restrict__ WqrT,
    const float* __restrict__ bq, const float* __restrict__ bk,
    const float* __restrict__ bv, const float* __restrict__ bqr,
    short* __restrict__ qkv, short* __restrict__ qrb, short* __restrict__ vT) {
  __shared__ short As[64 * 72];
  __shared__ short Bs[64 * 72];
  const int m0 = blockIdx.x * 64;
  const int nb = blockIdx.y;
  const int mat = nb / 12, h0 = nb % 12;
  const short* __restrict__ Bp =
      (mat < 3) ? WbT + (size_t)mat * WT_N + (size_t)(h0 * 64) * 768
                : WqrT + (size_t)(h0 * 64) * 768;
  const float* __restrict__ bias =
      (mat == 0) ? bq + h0 * 64 : (mat == 1) ? bk + h0 * 64
      : (mat == 2) ? bv + h0 * 64 : bqr + h0 * 64;
  const int t = threadIdx.x;
  const int w = t >> 6, lane = t & 63;
  const int wm = (w >> 1) * 32, wn = (w & 1) * 32;
  const int lr = lane & 15, lk = lane >> 4;
  const int sr = t >> 2, sc = (t & 3) * 16;
  f32x4 acc[2][2] = {};
  for (int kk = 0; kk < 768; kk += 64) {
    {
      const short* src = xb + (size_t)(m0 + sr) * 768 + kk + sc;
      *reinterpret_cast<bf16x8*>(&As[sr * 72 + sc])     = *reinterpret_cast<const bf16x8*>(src);
      *reinterpret_cast<bf16x8*>(&As[sr * 72 + sc + 8]) = *reinterpret_cast<const bf16x8*>(src + 8);
      const short* srb = Bp + (size_t)sr * 768 + kk + sc;
      *reinterpret_cast<bf16x8*>(&Bs[sr * 72 + sc])     = *reinterpret_cast<const bf16x8*>(srb);
      *reinterpret_cast<bf16x8*>(&Bs[sr * 72 + sc + 8]) = *reinterpret_cast<const bf16x8*>(srb + 8);
    }
    __syncthreads();
#pragma unroll
    for (int ks = 0; ks < 2; ++ks) {
      int k0 = ks * 32 + lk * 8;
      bf16x8 a0 = *reinterpret_cast<const bf16x8*>(&As[(wm + lr) * 72 + k0]);
      bf16x8 a1 = *reinterpret_cast<const bf16x8*>(&As[(wm + 16 + lr) * 72 + k0]);
      bf16x8 b0 = *reinterpret_cast<const bf16x8*>(&Bs[(wn + lr) * 72 + k0]);
      bf16x8 b1 = *reinterpret_cast<const bf16x8*>(&Bs[(wn + 16 + lr) * 72 + k0]);
      acc[0][0] = MFMA16(a0, b0, acc[0][0]);
      acc[0][1] = MFMA16(a0, b1, acc[0][1]);
      acc[1][0] = MFMA16(a1, b0, acc[1][0]);
      acc[1][1] = MFMA16(a1, b1, acc[1][1]);
    }
    __syncthreads();
  }
  const int b_ = m0 >> 9;
#pragma unroll
  for (int mf = 0; mf < 2; ++mf)
#pragma unroll
    for (int nf = 0; nf < 2; ++nf) {
      int d = wn + nf * 16 + lr;
      float bv_ = bias[d];
#pragma unroll
      for (int reg = 0; reg < 4; ++reg) {
        int i = (m0 + wm + mf * 16 + lk * 4 + reg) & 511;
        float val = acc[mf][nf][reg] + bv_;
        if (mat == 2) {
          vT[((size_t)(b_ * NH + h0) * HD + d) * S + i] = f2bf(val);
        } else if (mat == 3) {
          qrb[((size_t)(b_ * NH + h0) * S + i) * 64 + d] = f2bf(val);
        } else {
          qkv[(size_t)mat * QKV_N + (size_t)((b_ * NH + h0) * S + i) * HD + d] = f2bf(val);
        }
      }
    }
}

// ---------------------------------------------------------------------------
// K3: PURE qk scores -> f16 [b][i][h][j], no mask (mask applied in relsm).
// ---------------------------------------------------------------------------
__global__ __launch_bounds__(256) void k_qk(const short* __restrict__ q,
                                            const short* __restrict__ kmat,
                                            __half* __restrict__ sc) {
  const int j0 = blockIdx.x * 64, i0 = blockIdx.y * 64;
  const int bh = blockIdx.z;
  const int b = bh / NH, hh = bh % NH;
  const short* __restrict__ qp = q + (size_t)(bh * S) * HD;
  const short* __restrict__ kp = kmat + (size_t)(bh * S) * HD;
  const int t = threadIdx.x;
  const int w = t >> 6, lane = t & 63;
  const int wm = (w >> 1) * 32, wn = (w & 1) * 32;
  const int lr = lane & 15, lk = lane >> 4;
  f32x4 acc[2][2] = {};
#pragma unroll
  for (int ks = 0; ks < 2; ++ks) {
    int k0 = ks * 32 + lk * 8;
    bf16x8 a0 = *reinterpret_cast<const bf16x8*>(qp + (size_t)(i0 + wm + lr) * 64 + k0);
    bf16x8 a1 = *reinterpret_cast<const bf16x8*>(qp + (size_t)(i0 + wm + 16 + lr) * 64 + k0);
    bf16x8 b0 = *reinterpret_cast<const bf16x8*>(kp + (size_t)(j0 + wn + lr) * 64 + k0);
    bf16x8 b1 = *reinterpret_cast<const bf16x8*>(kp + (size_t)(j0 + wn + 16 + lr) * 64 + k0);
    acc[0][0] = MFMA16(a0, b0, acc[0][0]);
    acc[0][1] = MFMA16(a0, b1, acc[0][1]);
    acc[1][0] = MFMA16(a1, b0, acc[1][0]);
    acc[1][1] = MFMA16(a1, b1, acc[1][1]);
  }
#pragma unroll
  for (int mf = 0; mf < 2; ++mf)
#pragma unroll
    for (int nf = 0; nf < 2; ++nf) {
      int j = j0 + wn + nf * 16 + lr;
#pragma unroll
      for (int reg = 0; reg < 4; ++reg) {
        int i = i0 + wm + mf * 16 + lk * 4 + reg;
        sc[(((size_t)b * S + i) * NH + hh) * S + j] = __float2half(acc[mf][nf][reg] * 0.125f);
      }
    }
}

// ---------------------------------------------------------------------------
// K4: per (b,i): s = sc[h,j] + mask[j] + qr.rel^T; p = exp(min(s,80));
// den-reduce; probs bf16. Mask row staged once per block.
// ---------------------------------------------------------------------------
__global__ __launch_bounds__(256) void k_relsm(const short* __restrict__ qrb,
                                               const float* __restrict__ rel,
                                               const __half* __restrict__ sc,
                                               const float* __restrict__ graph,
                                               const float* __restrict__ endm,
                                               short* __restrict__ probs) {
  __shared__ short sq[16 * 520];
  __shared__ float mask_lds[512];
  __shared__ float den_lds[64];
  const int i = blockIdx.x, b = blockIdx.y;
  const int t = threadIdx.x;
  const int w = t >> 6, lane = t & 63;
  const int lr = lane & 15, fq = lane >> 4;
  {
    const short* src = reinterpret_cast<const short*>(sc + ((size_t)(b * S) + i) * NH * S);
    int hh = t >> 4, js = (t & 15) * 32;
    const short* sp = src + (size_t)hh * S + js;
    short* dp = &sq[hh * 520 + js];
#pragma unroll
    for (int c = 0; c < 4; ++c)
      *reinterpret_cast<bf16x8*>(dp + c * 8) = *reinterpret_cast<const bf16x8*>(sp + c * 8);
  }
  {
    int j = t * 2;
    float2 g = *reinterpret_cast<const float2*>(graph + ((size_t)b * S + i) * S + j);
    float2 e = *reinterpret_cast<const float2*>(endm + (size_t)b * S + j);
    mask_lds[j]     = (1.0f - g.x - e.x) * (-30000.0f);
    mask_lds[j + 1] = (1.0f - g.y - e.y) * (-30000.0f);
  }
  const int hA = (lr < NH) ? lr : 0;
  const short* qrow = qrb + ((size_t)(b * NH + hA) * S + i) * 64;
  bf16x8 a0 = *reinterpret_cast<const bf16x8*>(qrow + fq * 8);
  bf16x8 a1 = *reinterpret_cast<const bf16x8*>(qrow + 32 + fq * 8);
  const float* rp = rel + (((size_t)(b * S) + i) * S + (size_t)(w * 128 + lr)) * 64 + fq * 8;
  float p[8][4];
  float den[4] = {0.f, 0.f, 0.f, 0.f};
  f32x4 c0 = ld4nt(rp), c1 = ld4nt(rp + 4), c2 = ld4nt(rp + 32), c3 = ld4nt(rp + 36);
  __syncthreads();
#pragma unroll
  for (int tt = 0; tt < 8; ++tt) {
    f32x4 n0, n1, n2, n3;
    if (tt < 7) {
      const float* rn = rp + (size_t)(tt + 1) * 1024;
      n0 = ld4nt(rn); n1 = ld4nt(rn + 4); n2 = ld4nt(rn + 32); n3 = ld4nt(rn + 36);
    }
    bf16x8 b0 = cvt8(c0, c1), b1 = cvt8(c2, c3);
    f32x4 acc = {};
    acc = MFMA16(a0, b0, acc);
    acc = MFMA16(a1, b1, acc);
    const int j0 = w * 128 + tt * 16;
    const float mval = mask_lds[j0 + lr];
#pragma unroll
    for (int r = 0; r < 4; ++r) {
      int h = fq * 4 + r;
      float s = acc[r] + h2f(sq[h * 520 + j0 + lr]) + mval;
      float pe = __expf(fminf(s, 80.0f));
      den[r] += pe;
      p[tt][r] = pe;
    }
    if (tt < 7) { c0 = n0; c1 = n1; c2 = n2; c3 = n3; }
  }
#pragma unroll
  for (int r = 0; r < 4; ++r) {
    float d = den[r];
    d += __shfl_xor(d, 1); d += __shfl_xor(d, 2);
    d += __shfl_xor(d, 4); d += __shfl_xor(d, 8);
    den[r] = d;
  }
  if (lr == 0) {
#pragma unroll
    for (int r = 0; r < 4; ++r) den_lds[w * 16 + fq * 4 + r] = den[r];
  }
  __syncthreads();
  float invd[4];
#pragma unroll
  for (int r = 0; r < 4; ++r) {
    int h = fq * 4 + r;
    invd[r] = 1.0f / (den_lds[h] + den_lds[16 + h] + den_lds[32 + h] + den_lds[48 + h]);
  }
#pragma unroll
  for (int tt = 0; tt < 8; ++tt) {
    int j0 = w * 128 + tt * 16;
#pragma unroll
    for (int r = 0; r < 4; ++r) {
      int h = fq * 4 + r;
      if (h < NH)
        probs[((size_t)(b * NH + h) * S + i) * S + j0 + lr] = f2bf(p[tt][r] * invd[r]);
    }
  }
}

// ---------------------------------------------------------------------------
// K5: ctx = probs @ v via MFMA, LDS-free (vT[b,h,d,j]).
// ---------------------------------------------------------------------------
__global__ __launch_bounds__(256) void k_pv2(const short* __restrict__ probs,
                                             const short* __restrict__ vT,
                                             float* __restrict__ out) {
  const int i0 = blockIdx.x * 32;
  const int h = blockIdx.y, b = blockIdx.z;
  const short* __restrict__ pp  = probs + (size_t)((b * NH + h) * S) * S;
  const short* __restrict__ vtp = vT + (size_t)((b * NH + h) * HD) * S;
  const int t = threadIdx.x;
  const int w = t >> 6, lane = t & 63;
  const int wm = (w >> 1) * 16, wn = (w & 1) * 32;
  const int lr = lane & 15, lk = lane >> 4;
  f32x4 acc[2] = {};
#pragma unroll
  for (int j0 = 0; j0 < S; j0 += 64) {
#pragma unroll
    for (int ks = 0; ks < 2; ++ks) {
      int k0 = j0 + ks * 32 + lk * 8;
      bf16x8 a0 = *reinterpret_cast<const bf16x8*>(pp + (size_t)(i0 + wm + lr) * S + k0);
      bf16x8 b0 = *reinterpret_cast<const bf16x8*>(vtp + (size_t)(wn + lr) * S + k0);
      bf16x8 b1 = *reinterpret_cast<const bf16x8*>(vtp + (size_t)(wn + 16 + lr) * S + k0);
      acc[0] = MFMA16(a0, b0, acc[0]);
      acc[1] = MFMA16(a0, b1, acc[1]);
    }
  }
#pragma unroll
  for (int nf = 0; nf < 2; ++nf) {
    int d = wn + nf * 16 + lr;
#pragma unroll
    for (int reg = 0; reg < 4; ++reg) {
      int i = i0 + wm + lk * 4 + reg;
      out[((size_t)(b * S) + i) * HID + h * 64 + d] = acc[nf][reg];
    }
  }
}

// ---------------------------------------------------------------------------
extern "C" void kernel_launch(void* const* d_in, const int* in_sizes, int n_in,
                              void* d_out, int out_size, void* d_ws, size_t ws_size,
                              hipStream_t stream) {
  const float* x     = (const float*)d_in[0];
  const float* graph = (const float*)d_in[1];
  const float* endm  = (const float*)d_in[2];
  const float* rel   = (const float*)d_in[3];
  const float* Wq = (const float*)d_in[4];  const float* bq = (const float*)d_in[5];
  const float* Wk = (const float*)d_in[6];  const float* bk = (const float*)d_in[7];
  const float* Wv = (const float*)d_in[8];  const float* bv = (const float*)d_in[9];
  const float* Wr = (const float*)d_in[10]; // br dropped: softmax-invariant

  short* xb   = (short*)d_ws;                    // bf16 x   [2048][768]
  short* WbT  = xb + XB_N;                       // bf16 W^T x3
  short* WqrT = WbT + 3 * WT_N;                  // bf16 combined qr weight
  float* bqr  = (float*)(WqrT + WT_N);
  short* qb   = (short*)(bqr + 768);
  short* kb   = qb + QKV_N;
  short* vTb  = kb + QKV_N;                      // v transposed [b][h][d][j]
  short* qrb  = vTb + QKV_N;
  __half* scores = (__half*)(qrb + QKV_N);       // f16, [b][i][h][j] (unmasked)
  short* probs   = (short*)(scores + SCORES_N);  // bf16, [b][h][i][j]
  const size_t need = (size_t)(XB_N + 4 * WT_N) * 2 + 768 * 4 +
                      (size_t)4 * QKV_N * 2 + SCORES_N * 2 + SCORES_N * 2;
  if (ws_size < need) return;

  k_prep<<<dim3(1212), 256, 0, stream>>>(x, Wq, Wk, Wv, Wr, bq, xb, WbT, WqrT, bqr);
  k_qkv3<<<dim3(32, 48), 256, 0, stream>>>(xb, WbT, WqrT, bq, bk, bv, bqr, qb, qrb, vTb);
  k_qk<<<dim3(8, 8, B * NH), 256, 0, stream>>>(qb, kb, scores);
  k_relsm<<<dim3(S, B), 256, 0, stream>>>(qrb, rel, scores, graph, endm, probs);
  k_pv2<<<dim3(16, NH, B), 256, 0, stream>>>(probs, vTb, (float*)d_out);
}